// Round 4
// baseline (535.265 us; speedup 1.0000x reference)
//
#include <hip/hip_runtime.h>

// Keep float semantics deterministic (no FMA contraction anywhere).
#pragma clang fp contract(off)

#define DD 128
#define NCELL (DD * DD * DD)
#define CPT 4

// Neighbor m (0..25) -> 3x3x3 index skipping center (13).
__device__ __forceinline__ void nbr_off(int m, int& di, int& dj, int& dk) {
    const int idx = (m < 13) ? m : m + 1;
    di = idx / 9 - 1;
    dj = (idx / 3) % 3 - 1;
    dk = idx % 3 - 1;
}

// ---------------- K1: dense streaming pass + compaction ----------------
__global__ __launch_bounds__(256) void k1_dense(
    const float* __restrict__ x,    // [NCELL][5]
    const float* __restrict__ out,  // [NCELL][8]
    float* __restrict__ y,          // [NCELL][5]
    int* __restrict__ counter,      // ws[0]
    int* __restrict__ list)         // ws + 64B
{
    const int t  = blockIdx.x * blockDim.x + threadIdx.x;
    const int n0 = t * CPT;
    if (n0 >= NCELL) return;

    float4 xa[5], oa[8];
    const float4* xp = reinterpret_cast<const float4*>(x) + (size_t)t * 5;
    const float4* op = reinterpret_cast<const float4*>(out) + (size_t)t * 8;
#pragma unroll
    for (int q = 0; q < 5; ++q) xa[q] = xp[q];
#pragma unroll
    for (int q = 0; q < 8; ++q) oa[q] = op[q];

    float xv[20], ov[32], rv[20];
#pragma unroll
    for (int q = 0; q < 5; ++q) {
        xv[q * 4 + 0] = xa[q].x; xv[q * 4 + 1] = xa[q].y;
        xv[q * 4 + 2] = xa[q].z; xv[q * 4 + 3] = xa[q].w;
    }
#pragma unroll
    for (int q = 0; q < 8; ++q) {
        ov[q * 4 + 0] = oa[q].x; ov[q * 4 + 1] = oa[q].y;
        ov[q * 4 + 2] = oa[q].z; ov[q * 4 + 3] = oa[q].w;
    }

    const int lane = threadIdx.x & 63;

#pragma unroll
    for (int c = 0; c < CPT; ++c) {
        const int s0 = (int)xv[c * 5 + 0];

        // argmax over out[..., 0:4], first-occurrence (strict >)
        float b = ov[c * 8 + 0];
        int   s1 = 0;
        if (ov[c * 8 + 1] > b) { b = ov[c * 8 + 1]; s1 = 1; }
        if (ov[c * 8 + 2] > b) { b = ov[c * 8 + 2]; s1 = 2; }
        if (ov[c * 8 + 3] > b) { b = ov[c * 8 + 3]; s1 = 3; }
        if (s0 == 0) s1 = 0;

        float f1 = ov[c * 8 + 7];
        float e0 = xv[c * 5 + 1], e1 = xv[c * 5 + 2], e2 = xv[c * 5 + 3];

        if (s1 <= 1) {
            f1 = -1.0f; e0 = -1.0f; e1 = -1.0f; e2 = -1.0f;
        } else if (s1 == 2) {
            f1 = fminf(fmaxf(f1, 0.0f), 0.92f);
        } else {
            f1 = 1.0f;
        }

        // Append solidify cells to the compact list (wave-aggregated atomic).
        const bool flag = (s0 <= 1 && s1 > 1);
        const unsigned long long mask = __ballot(flag);
        if (flag) {
            const int lead = __ffsll(mask) - 1;
            const unsigned long long lt = mask & ((1ull << lane) - 1ull);
            int base = 0;
            if (lane == lead) base = atomicAdd(counter, (int)__popcll(mask));
            base = __shfl(base, lead, 64);
            list[base + (int)__popcll(lt)] = n0 + c;
        }

        rv[c * 5 + 0] = (float)s1;
        rv[c * 5 + 1] = e0;
        rv[c * 5 + 2] = e1;
        rv[c * 5 + 3] = e2;
        rv[c * 5 + 4] = f1;
    }

    float4* yp = reinterpret_cast<float4*>(y) + (size_t)t * 5;
#pragma unroll
    for (int q = 0; q < 5; ++q) {
        float4 v;
        v.x = rv[q * 4 + 0]; v.y = rv[q * 4 + 1];
        v.z = rv[q * 4 + 2]; v.w = rv[q * 4 + 3];
        yp[q] = v;
    }
}

// ---------------- K2: compacted 26-neighbor argmin, full lane density ----------------
__global__ __launch_bounds__(256) void k2_gather(
    const float* __restrict__ x,
    const float* __restrict__ out,
    float* __restrict__ y,
    const int* __restrict__ counter,
    const int* __restrict__ list)
{
    const int cnt    = counter[0];
    const int stride = gridDim.x * blockDim.x;
    for (int i = blockIdx.x * blockDim.x + threadIdx.x; i < cnt; i += stride) {
        const int n  = list[i];
        const int k  = n & (DD - 1);
        const int j  = (n >> 7) & (DD - 1);
        const int i0 = n >> 14;

        // rot0..2 live at out[n*8+4..6]; 16B-aligned -> one float4 load.
        const float4 rot = *reinterpret_cast<const float4*>(out + (size_t)n * 8 + 4);
        const double r0 = (double)rot.x, r1 = (double)rot.y, r2 = (double)rot.z;

        // Batch-issue all 26 neighbor loads (independent -> deep MLP).
        float av[26][3];
#pragma unroll
        for (int m = 0; m < 26; ++m) {
            int di, dj, dk;
            nbr_off(m, di, dj, dk);
            const int ii = i0 + di, jj = j + dj, kk = k + dk;
            av[m][0] = 0.0f; av[m][1] = 0.0f; av[m][2] = 0.0f;
            if ((unsigned)ii < (unsigned)DD &&
                (unsigned)jj < (unsigned)DD &&
                (unsigned)kk < (unsigned)DD) {
                const float* p = x + ((size_t)((ii * DD + jj) * DD + kk)) * 5 + 1;
                av[m][0] = p[0]; av[m][1] = p[1]; av[m][2] = p[2];
            }
        }

        // f64 distances: ordering matches float64 numpy argmin (first-occurrence).
        double best = 1.0e300;
        float ce0 = 0.0f, ce1 = 0.0f, ce2 = 0.0f;
#pragma unroll
        for (int m = 0; m < 26; ++m) {
            const double d0 = (double)av[m][0] - r0;
            const double d1 = (double)av[m][1] - r1;
            const double d2 = (double)av[m][2] - r2;
            const double dist = d0 * d0 + d1 * d1 + d2 * d2;
            if (dist < best) { best = dist; ce0 = av[m][0]; ce1 = av[m][1]; ce2 = av[m][2]; }
        }

        float* yp = y + (size_t)n * 5;
        yp[1] = ce0; yp[2] = ce1; yp[3] = ce2;
    }
}

// ---------------- Fallback: proven single-kernel path (R2) ----------------
__global__ __launch_bounds__(256) void cafe_rnn_fallback(
    const float* __restrict__ x,
    const float* __restrict__ out,
    float* __restrict__ y)
{
    const int t  = blockIdx.x * blockDim.x + threadIdx.x;
    const int n0 = t * CPT;
    if (n0 >= NCELL) return;

    float4 xa[5], oa[8];
    const float4* xp = reinterpret_cast<const float4*>(x) + (size_t)t * 5;
    const float4* op = reinterpret_cast<const float4*>(out) + (size_t)t * 8;
#pragma unroll
    for (int q = 0; q < 5; ++q) xa[q] = xp[q];
#pragma unroll
    for (int q = 0; q < 8; ++q) oa[q] = op[q];

    float xv[20], ov[32], rv[20];
#pragma unroll
    for (int q = 0; q < 5; ++q) {
        xv[q * 4 + 0] = xa[q].x; xv[q * 4 + 1] = xa[q].y;
        xv[q * 4 + 2] = xa[q].z; xv[q * 4 + 3] = xa[q].w;
    }
#pragma unroll
    for (int q = 0; q < 8; ++q) {
        ov[q * 4 + 0] = oa[q].x; ov[q * 4 + 1] = oa[q].y;
        ov[q * 4 + 2] = oa[q].z; ov[q * 4 + 3] = oa[q].w;
    }

#pragma unroll
    for (int c = 0; c < CPT; ++c) {
        const int s0 = (int)xv[c * 5 + 0];
        float b = ov[c * 8 + 0];
        int   s1 = 0;
        if (ov[c * 8 + 1] > b) { b = ov[c * 8 + 1]; s1 = 1; }
        if (ov[c * 8 + 2] > b) { b = ov[c * 8 + 2]; s1 = 2; }
        if (ov[c * 8 + 3] > b) { b = ov[c * 8 + 3]; s1 = 3; }
        if (s0 == 0) s1 = 0;

        float f1 = ov[c * 8 + 7];
        float e0 = xv[c * 5 + 1], e1 = xv[c * 5 + 2], e2 = xv[c * 5 + 3];
        if (s1 <= 1) { f1 = -1.0f; e0 = -1.0f; e1 = -1.0f; e2 = -1.0f; }
        else if (s1 == 2) { f1 = fminf(fmaxf(f1, 0.0f), 0.92f); }
        else { f1 = 1.0f; }

        if (s0 <= 1 && s1 > 1) {
            const int n = n0 + c;
            const int k = n & (DD - 1);
            const int j = (n >> 7) & (DD - 1);
            const int i = (n >> 14);
            const double r0 = (double)ov[c * 8 + 4];
            const double r1 = (double)ov[c * 8 + 5];
            const double r2 = (double)ov[c * 8 + 6];
            double best = 1.0e300;
            float ce0 = 0.0f, ce1 = 0.0f, ce2 = 0.0f;
#pragma unroll
            for (int m = 0; m < 26; ++m) {
                int di, dj, dk;
                nbr_off(m, di, dj, dk);
                const int ii = i + di, jj = j + dj, kk = k + dk;
                float a0 = 0.0f, a1 = 0.0f, a2 = 0.0f;
                if ((unsigned)ii < (unsigned)DD &&
                    (unsigned)jj < (unsigned)DD &&
                    (unsigned)kk < (unsigned)DD) {
                    const float* p = x + ((size_t)((ii * DD + jj) * DD + kk)) * 5 + 1;
                    a0 = p[0]; a1 = p[1]; a2 = p[2];
                }
                const double d0 = (double)a0 - r0;
                const double d1 = (double)a1 - r1;
                const double d2 = (double)a2 - r2;
                const double dist = d0 * d0 + d1 * d1 + d2 * d2;
                if (dist < best) { best = dist; ce0 = a0; ce1 = a1; ce2 = a2; }
            }
            e0 = ce0; e1 = ce1; e2 = ce2;
        }

        rv[c * 5 + 0] = (float)s1;
        rv[c * 5 + 1] = e0;
        rv[c * 5 + 2] = e1;
        rv[c * 5 + 3] = e2;
        rv[c * 5 + 4] = f1;
    }

    float4* yp = reinterpret_cast<float4*>(y) + (size_t)t * 5;
#pragma unroll
    for (int q = 0; q < 5; ++q) {
        float4 v;
        v.x = rv[q * 4 + 0]; v.y = rv[q * 4 + 1];
        v.z = rv[q * 4 + 2]; v.w = rv[q * 4 + 3];
        yp[q] = v;
    }
}

extern "C" void kernel_launch(void* const* d_in, const int* in_sizes, int n_in,
                              void* d_out, int out_size, void* d_ws, size_t ws_size,
                              hipStream_t stream) {
    const float* x   = (const float*)d_in[0];
    const float* out = (const float*)d_in[1];
    float* y = (float*)d_out;

    const int threads = 256;
    const int blocks1 = NCELL / (threads * CPT); // 2048

    const size_t need = 64 + (size_t)NCELL * sizeof(int);
    if (ws_size >= need) {
        int* counter = (int*)d_ws;
        int* list    = (int*)((char*)d_ws + 64);
        hipMemsetAsync(d_ws, 0, 64, stream); // ws re-poisoned to 0xAA each call
        k1_dense<<<blocks1, threads, 0, stream>>>(x, out, y, counter, list);
        k2_gather<<<1024, threads, 0, stream>>>(x, out, y, counter, list);
    } else {
        cafe_rnn_fallback<<<blocks1, threads, 0, stream>>>(x, out, y);
    }
}

// Round 5
// 167.419 us; speedup vs baseline: 3.1972x; 3.1972x over previous
//
#include <hip/hip_runtime.h>

// Keep float semantics deterministic (no FMA contraction anywhere).
#pragma clang fp contract(off)

#define DD 128
#define NCELL (DD * DD * DD)
#define CPT 4
#define NWAVE (NCELL / 256)   // 8192 waves, each owning 256 cells

// Neighbor m (0..25) -> 3x3x3 index skipping center (13).
__device__ __forceinline__ void nbr_off(int m, int& di, int& dj, int& dk) {
    const int idx = (m < 13) ? m : m + 1;
    di = idx / 9 - 1;
    dj = (idx / 3) % 3 - 1;
    dk = idx % 3 - 1;
}

// ---------------- K1: dense streaming pass + atomic-free compaction ----------------
// Wave w (= global thread id >> 6) owns cells [w*256, w*256+256) and list
// slots [w*256, w*256+256). Compaction is ballot/popc only — no atomics.
__global__ __launch_bounds__(256) void k1_dense(
    const float* __restrict__ x,    // [NCELL][5]
    const float* __restrict__ out,  // [NCELL][8]
    float* __restrict__ y,          // [NCELL][5]
    int* __restrict__ wcnt,         // [NWAVE]
    int* __restrict__ list)         // [NCELL]
{
    const int t  = blockIdx.x * blockDim.x + threadIdx.x;
    const int n0 = t * CPT;
    if (n0 >= NCELL) return;

    const int w    = t >> 6;
    const int lane = threadIdx.x & 63;
    const unsigned long long lt = (1ull << lane) - 1ull;

    float4 xa[5], oa[8];
    const float4* xp = reinterpret_cast<const float4*>(x) + (size_t)t * 5;
    const float4* op = reinterpret_cast<const float4*>(out) + (size_t)t * 8;
#pragma unroll
    for (int q = 0; q < 5; ++q) xa[q] = xp[q];
#pragma unroll
    for (int q = 0; q < 8; ++q) oa[q] = op[q];

    float xv[20], ov[32], rv[20];
#pragma unroll
    for (int q = 0; q < 5; ++q) {
        xv[q * 4 + 0] = xa[q].x; xv[q * 4 + 1] = xa[q].y;
        xv[q * 4 + 2] = xa[q].z; xv[q * 4 + 3] = xa[q].w;
    }
#pragma unroll
    for (int q = 0; q < 8; ++q) {
        ov[q * 4 + 0] = oa[q].x; ov[q * 4 + 1] = oa[q].y;
        ov[q * 4 + 2] = oa[q].z; ov[q * 4 + 3] = oa[q].w;
    }

    unsigned total = 0;  // running compacted count within this wave

#pragma unroll
    for (int c = 0; c < CPT; ++c) {
        const int s0 = (int)xv[c * 5 + 0];

        // argmax over out[..., 0:4], first-occurrence (strict >)
        float b = ov[c * 8 + 0];
        int   s1 = 0;
        if (ov[c * 8 + 1] > b) { b = ov[c * 8 + 1]; s1 = 1; }
        if (ov[c * 8 + 2] > b) { b = ov[c * 8 + 2]; s1 = 2; }
        if (ov[c * 8 + 3] > b) { b = ov[c * 8 + 3]; s1 = 3; }
        if (s0 == 0) s1 = 0;

        float f1 = ov[c * 8 + 7];
        float e0 = xv[c * 5 + 1], e1 = xv[c * 5 + 2], e2 = xv[c * 5 + 3];

        if (s1 <= 1) {
            f1 = -1.0f; e0 = -1.0f; e1 = -1.0f; e2 = -1.0f;
        } else if (s1 == 2) {
            f1 = fminf(fmaxf(f1, 0.0f), 0.92f);
        } else {
            f1 = 1.0f;
        }

        // Wave-private compaction: no atomics, pure ballot arithmetic.
        const bool flag = (s0 <= 1 && s1 > 1);
        const unsigned long long mask = __ballot(flag);
        if (flag) {
            const int pos = (int)total + (int)__popcll(mask & lt);
            list[(w << 8) + pos] = n0 + c;
        }
        total += (unsigned)__popcll(mask);

        rv[c * 5 + 0] = (float)s1;
        rv[c * 5 + 1] = e0;
        rv[c * 5 + 2] = e1;
        rv[c * 5 + 3] = e2;
        rv[c * 5 + 4] = f1;
    }

    if (lane == 0) wcnt[w] = (int)total;

    float4* yp = reinterpret_cast<float4*>(y) + (size_t)t * 5;
#pragma unroll
    for (int q = 0; q < 5; ++q) {
        float4 v;
        v.x = rv[q * 4 + 0]; v.y = rv[q * 4 + 1];
        v.z = rv[q * 4 + 2]; v.w = rv[q * 4 + 3];
        yp[q] = v;
    }
}

// ---------------- K2: per-segment 26-neighbor argmin, full lane density ----------------
__global__ __launch_bounds__(256) void k2_gather(
    const float* __restrict__ x,
    const float* __restrict__ out,
    float* __restrict__ y,
    const int* __restrict__ wcnt,
    const int* __restrict__ list)
{
    const int seg = blockIdx.x;
    const int cnt = wcnt[seg];

    for (int i = threadIdx.x; i < cnt; i += 256) {
        const int n  = list[(seg << 8) + i];
        const int k  = n & (DD - 1);
        const int j  = (n >> 7) & (DD - 1);
        const int i0 = n >> 14;

        // rot0..2 at out[n*8+4..6]; 16B-aligned float4.
        const float4 rot = *reinterpret_cast<const float4*>(out + (size_t)n * 8 + 4);
        const double r0 = (double)rot.x, r1 = (double)rot.y, r2 = (double)rot.z;

        // Batch-issue all 26 neighbor loads (independent -> deep MLP).
        float av[26][3];
#pragma unroll
        for (int m = 0; m < 26; ++m) {
            int di, dj, dk;
            nbr_off(m, di, dj, dk);
            const int ii = i0 + di, jj = j + dj, kk = k + dk;
            av[m][0] = 0.0f; av[m][1] = 0.0f; av[m][2] = 0.0f;
            if ((unsigned)ii < (unsigned)DD &&
                (unsigned)jj < (unsigned)DD &&
                (unsigned)kk < (unsigned)DD) {
                const float* p = x + ((size_t)((ii * DD + jj) * DD + kk)) * 5 + 1;
                av[m][0] = p[0]; av[m][1] = p[1]; av[m][2] = p[2];
            }
        }

        // f64 distances: ordering matches float64 numpy argmin (first-occurrence).
        double best = 1.0e300;
        float ce0 = 0.0f, ce1 = 0.0f, ce2 = 0.0f;
#pragma unroll
        for (int m = 0; m < 26; ++m) {
            const double d0 = (double)av[m][0] - r0;
            const double d1 = (double)av[m][1] - r1;
            const double d2 = (double)av[m][2] - r2;
            const double dist = d0 * d0 + d1 * d1 + d2 * d2;
            if (dist < best) { best = dist; ce0 = av[m][0]; ce1 = av[m][1]; ce2 = av[m][2]; }
        }

        float* yp = y + (size_t)n * 5;
        yp[1] = ce0; yp[2] = ce1; yp[3] = ce2;
    }
}

// ---------------- Fallback: proven single-kernel path (R2, 82.9 us) ----------------
__global__ __launch_bounds__(256) void cafe_rnn_fallback(
    const float* __restrict__ x,
    const float* __restrict__ out,
    float* __restrict__ y)
{
    const int t  = blockIdx.x * blockDim.x + threadIdx.x;
    const int n0 = t * CPT;
    if (n0 >= NCELL) return;

    float4 xa[5], oa[8];
    const float4* xp = reinterpret_cast<const float4*>(x) + (size_t)t * 5;
    const float4* op = reinterpret_cast<const float4*>(out) + (size_t)t * 8;
#pragma unroll
    for (int q = 0; q < 5; ++q) xa[q] = xp[q];
#pragma unroll
    for (int q = 0; q < 8; ++q) oa[q] = op[q];

    float xv[20], ov[32], rv[20];
#pragma unroll
    for (int q = 0; q < 5; ++q) {
        xv[q * 4 + 0] = xa[q].x; xv[q * 4 + 1] = xa[q].y;
        xv[q * 4 + 2] = xa[q].z; xv[q * 4 + 3] = xa[q].w;
    }
#pragma unroll
    for (int q = 0; q < 8; ++q) {
        ov[q * 4 + 0] = oa[q].x; ov[q * 4 + 1] = oa[q].y;
        ov[q * 4 + 2] = oa[q].z; ov[q * 4 + 3] = oa[q].w;
    }

#pragma unroll
    for (int c = 0; c < CPT; ++c) {
        const int s0 = (int)xv[c * 5 + 0];
        float b = ov[c * 8 + 0];
        int   s1 = 0;
        if (ov[c * 8 + 1] > b) { b = ov[c * 8 + 1]; s1 = 1; }
        if (ov[c * 8 + 2] > b) { b = ov[c * 8 + 2]; s1 = 2; }
        if (ov[c * 8 + 3] > b) { b = ov[c * 8 + 3]; s1 = 3; }
        if (s0 == 0) s1 = 0;

        float f1 = ov[c * 8 + 7];
        float e0 = xv[c * 5 + 1], e1 = xv[c * 5 + 2], e2 = xv[c * 5 + 3];
        if (s1 <= 1) { f1 = -1.0f; e0 = -1.0f; e1 = -1.0f; e2 = -1.0f; }
        else if (s1 == 2) { f1 = fminf(fmaxf(f1, 0.0f), 0.92f); }
        else { f1 = 1.0f; }

        if (s0 <= 1 && s1 > 1) {
            const int n = n0 + c;
            const int k = n & (DD - 1);
            const int j = (n >> 7) & (DD - 1);
            const int i = (n >> 14);
            const double r0 = (double)ov[c * 8 + 4];
            const double r1 = (double)ov[c * 8 + 5];
            const double r2 = (double)ov[c * 8 + 6];
            double best = 1.0e300;
            float ce0 = 0.0f, ce1 = 0.0f, ce2 = 0.0f;
#pragma unroll
            for (int m = 0; m < 26; ++m) {
                int di, dj, dk;
                nbr_off(m, di, dj, dk);
                const int ii = i + di, jj = j + dj, kk = k + dk;
                float a0 = 0.0f, a1 = 0.0f, a2 = 0.0f;
                if ((unsigned)ii < (unsigned)DD &&
                    (unsigned)jj < (unsigned)DD &&
                    (unsigned)kk < (unsigned)DD) {
                    const float* p = x + ((size_t)((ii * DD + jj) * DD + kk)) * 5 + 1;
                    a0 = p[0]; a1 = p[1]; a2 = p[2];
                }
                const double d0 = (double)a0 - r0;
                const double d1 = (double)a1 - r1;
                const double d2 = (double)a2 - r2;
                const double dist = d0 * d0 + d1 * d1 + d2 * d2;
                if (dist < best) { best = dist; ce0 = a0; ce1 = a1; ce2 = a2; }
            }
            e0 = ce0; e1 = ce1; e2 = ce2;
        }

        rv[c * 5 + 0] = (float)s1;
        rv[c * 5 + 1] = e0;
        rv[c * 5 + 2] = e1;
        rv[c * 5 + 3] = e2;
        rv[c * 5 + 4] = f1;
    }

    float4* yp = reinterpret_cast<float4*>(y) + (size_t)t * 5;
#pragma unroll
    for (int q = 0; q < 5; ++q) {
        float4 v;
        v.x = rv[q * 4 + 0]; v.y = rv[q * 4 + 1];
        v.z = rv[q * 4 + 2]; v.w = rv[q * 4 + 3];
        yp[q] = v;
    }
}

extern "C" void kernel_launch(void* const* d_in, const int* in_sizes, int n_in,
                              void* d_out, int out_size, void* d_ws, size_t ws_size,
                              hipStream_t stream) {
    const float* x   = (const float*)d_in[0];
    const float* out = (const float*)d_in[1];
    float* y = (float*)d_out;

    const int threads = 256;
    const int blocks1 = NCELL / (threads * CPT); // 2048

    // ws layout: wcnt[NWAVE] (32 KB) | list[NCELL] (8 MB). Every wcnt entry is
    // written by k1 (grid exactly covers all waves) -> no memset needed.
    const size_t need = (size_t)NWAVE * sizeof(int) + (size_t)NCELL * sizeof(int);
    if (ws_size >= need) {
        int* wcnt = (int*)d_ws;
        int* list = (int*)((char*)d_ws + (size_t)NWAVE * sizeof(int));
        k1_dense<<<blocks1, threads, 0, stream>>>(x, out, y, wcnt, list);
        k2_gather<<<NWAVE, threads, 0, stream>>>(x, out, y, wcnt, list);
    } else {
        cafe_rnn_fallback<<<blocks1, threads, 0, stream>>>(x, out, y);
    }
}